// Round 6
// baseline (351.214 us; speedup 1.0000x reference)
//
#include <hip/hip_runtime.h>
#include <stdint.h>

#define T_SEQ 2048
#define DM    2048
#define NH    16
#define NKV   4
#define HD    128
#define MROWS 4096          // B*T
#define NQKV  3072          // 16*128 + 4*128 + 4*128

typedef unsigned short u16;
typedef __bf16 bf16x8 __attribute__((ext_vector_type(8)));
typedef float  f32x4  __attribute__((ext_vector_type(4)));
typedef u16    u16x8  __attribute__((ext_vector_type(8)));

__device__ __forceinline__ u16 f2b(float f) {
  union { float f; unsigned u; } v; v.f = f;
  return (u16)((v.u + 0x7fffu + ((v.u >> 16) & 1u)) >> 16);
}
__device__ __forceinline__ float b2f(u16 u) {
  union { unsigned u; float f; } v; v.u = ((unsigned)u) << 16;
  return v.f;
}
// async global->LDS, 16B per lane; LDS dest = wave-uniform base + lane*16
__device__ __forceinline__ void gl_lds16(const u16* g, u16* l) {
  __builtin_amdgcn_global_load_lds(
      (__attribute__((address_space(1))) void*)g,
      (__attribute__((address_space(3))) void*)l, 16, 0, 0);
}
__device__ __forceinline__ void storev(float* p, float v) { *p = v; }
__device__ __forceinline__ void storev(u16* p, float v)   { *p = f2b(v); }

// ---- fp32 -> bf16 elementwise (x) ----
__global__ __launch_bounds__(256) void k_cvt_x(const float* __restrict__ x,
                                               u16* __restrict__ o, int n) {
  int i = (blockIdx.x * 256 + threadIdx.x) * 4;
  if (i >= n) return;
  float4 v = *(const float4*)(x + i);
  ushort4 r;
  r.x = f2b(v.x); r.y = f2b(v.y); r.z = f2b(v.z); r.w = f2b(v.w);
  *(ushort4*)(o + i) = r;
}

// ---- all four weight transposes in one launch ----
// z selects: [0,64) Wq -> WT, [64,80) Wk -> WT+2048*2048,
//            [80,96) Wv -> WT+2560*2048, [96,160) Wo -> Wot. Kd=2048 always.
__global__ __launch_bounds__(256) void k_tw4(const float* __restrict__ Wq,
                                             const float* __restrict__ Wk,
                                             const float* __restrict__ Wv,
                                             const float* __restrict__ Wo,
                                             u16* __restrict__ WT,
                                             u16* __restrict__ Wot) {
  __shared__ float tl[32][33];
  int z = blockIdx.z;
  const float* in; u16* out; int Nd, xt;
  if (z < 64)      { in = Wq; out = WT;               Nd = 2048; xt = z; }
  else if (z < 80) { in = Wk; out = WT + 2048 * 2048; Nd = 512;  xt = z - 64; }
  else if (z < 96) { in = Wv; out = WT + 2560 * 2048; Nd = 512;  xt = z - 80; }
  else             { in = Wo; out = Wot;              Nd = 2048; xt = z - 96; }
  int n0 = xt * 32, k0 = blockIdx.y * 32;
  int tx = threadIdx.x, ty = threadIdx.y;
#pragma unroll
  for (int i = 0; i < 32; i += 8)
    tl[ty + i][tx] = in[(long)(k0 + ty + i) * Nd + n0 + tx];
  __syncthreads();
#pragma unroll
  for (int i = 0; i < 32; i += 8)
    out[(long)(n0 + ty + i) * 2048 + k0 + tx] = f2b(tl[tx][ty + i]);
}

// ---- fused QKV GEMM: C = Xb * WT^T with RoPE/V-transpose epilogue ----
// m97 structure + chunk-XOR swizzle (r5: 0 conflicts). Each C-tile is 128 t
// x 128 d = exactly one head (by<16: Q head by; 16-19: K head; 20-23: V).
// Q/K epilogue: stage C-tile (two 64-row rounds) into the dead As/Bs LDS
// (stride 136 keeps ds 16B alignment), then apply RoPE pairs (d,d+64) and
// store final [B,H,T,HD] layout coalesced. Q pre-scaled by
// (1/sqrt(128))*log2(e) for the exp2-domain attention. V epilogue: direct
// transposed ushort4 stores (4 t-contiguous acc values) into Vt[B,KV,HD,T].
// Replaces the Cq intermediate + k_rope2 + k_vt (~50 MB HBM round-trip).
__global__ __launch_bounds__(256) void k_gemm_qkv(const u16* __restrict__ A,
                                                  const u16* __restrict__ Bt,
                                                  u16* __restrict__ Qo,
                                                  u16* __restrict__ Ko,
                                                  u16* __restrict__ Vo) {
  __shared__ __align__(16) u16 smem[64 * 136];   // 17408 B >= As+Bs (16384 B)
  u16* As = smem;
  u16* Bs = smem + 4096;
  const int tid = threadIdx.x;
  const int wv = tid >> 6, lane = tid & 63;
  const int quad = lane >> 4, ln = lane & 15;
  const int wm = wv & 1, wn = wv >> 1;
  const int rchnk = quad ^ ((ln >> 1) & 3);
  const int m0i = blockIdx.x * 128;
  const int by = blockIdx.y;
  const long m0 = m0i, n0 = (long)by * 128;
  f32x4 acc[4][4] = {};
  for (int k0 = 0; k0 < DM; k0 += 32) {
#pragma unroll
    for (int r = 0; r < 2; ++r) {
      int c = r * 256 + tid;
      int gc = (c & 3) ^ ((c >> 3) & 3);
      gl_lds16(A  + (m0 + (c >> 2)) * DM + k0 + gc * 8, &As[(r * 256 + wv * 64) * 8]);
      gl_lds16(Bt + (n0 + (c >> 2)) * DM + k0 + gc * 8, &Bs[(r * 256 + wv * 64) * 8]);
    }
    __syncthreads();
    bf16x8 af[4], bg[4];
#pragma unroll
    for (int i = 0; i < 4; ++i)
      af[i] = *(const bf16x8*)&As[(wm * 64 + i * 16 + ln) * 32 + rchnk * 8];
#pragma unroll
    for (int j = 0; j < 4; ++j)
      bg[j] = *(const bf16x8*)&Bs[(wn * 64 + j * 16 + ln) * 32 + rchnk * 8];
#pragma unroll
    for (int i = 0; i < 4; ++i)
#pragma unroll
      for (int j = 0; j < 4; ++j)
        acc[i][j] = __builtin_amdgcn_mfma_f32_16x16x32_bf16(af[i], bg[j], acc[i][j], 0, 0, 0);
    __syncthreads();
  }
  if (by < 20) {
    // ---- Q/K: RoPE epilogue via LDS round-trip, two 64-row rounds ----
    const bool isQ = by < 16;
    const int head = isQ ? by : by - 16;
    const int nh = isQ ? NH : NKV;
    const float qs = isQ ? 0.12751745f : 1.0f;   // (1/sqrt(128))*log2(e) | 1
    u16* dst = isQ ? Qo : Ko;
#pragma unroll
    for (int r0 = 0; r0 < 128; r0 += 64) {
      if (wm == (r0 >> 6)) {
#pragma unroll
        for (int i = 0; i < 4; ++i)
#pragma unroll
          for (int j = 0; j < 4; ++j)
#pragma unroll
            for (int r = 0; r < 4; ++r)
              smem[(i * 16 + quad * 4 + r) * 136 + wn * 64 + j * 16 + ln] =
                  f2b(acc[i][j][r]);
      }
      __syncthreads();
      int row = tid >> 2, dc = (tid & 3) * 16;
      int t = m0i + r0 + row;
      int t2 = t & (T_SEQ - 1), bb = t >> 11;
      const u16* cr = &smem[row * 136];
      long ob = ((long)(bb * nh + head) * T_SEQ + t2) * HD;
      u16x8 oA[2], oB[2];
#pragma unroll
      for (int g = 0; g < 2; ++g)
#pragma unroll
        for (int dd = 0; dd < 8; ++dd) {
          int d = dc + g * 8 + dd;
          float c1 = b2f(cr[d]), c2 = b2f(cr[d + 64]);
          float inv = __expf(-0.14391156f * (float)d);  // 10000^(-d/64)
          float sn, cn;
          __sincosf((float)t2 * inv, &sn, &cn);
          oA[g][dd] = f2b((c1 * cn - c2 * sn) * qs);
          oB[g][dd] = f2b((c2 * cn + c1 * sn) * qs);
        }
      *(u16x8*)&dst[ob + dc]          = oA[0];
      *(u16x8*)&dst[ob + dc + 8]      = oA[1];
      *(u16x8*)&dst[ob + 64 + dc]     = oB[0];
      *(u16x8*)&dst[ob + 64 + dc + 8] = oB[1];
      __syncthreads();
    }
  } else {
    // ---- V: direct transposed stores into Vt[B,KV,HD,T] ----
    const int kv = by - 20;
    const int bb = m0i >> 11, t0i = m0i & (T_SEQ - 1);
#pragma unroll
    for (int i = 0; i < 4; ++i)
#pragma unroll
      for (int j = 0; j < 4; ++j) {
        int d = wn * 64 + j * 16 + ln;
        int t = t0i + wm * 64 + i * 16 + quad * 4;
        long vo = ((long)((bb * NKV + kv) * HD) + d) * T_SEQ + t;
        ushort4 pk;
        pk.x = f2b(acc[i][j][0]); pk.y = f2b(acc[i][j][1]);
        pk.z = f2b(acc[i][j][2]); pk.w = f2b(acc[i][j][3]);
        *(ushort4*)&Vo[vo] = pk;
      }
  }
}

// ---- C[M][N] = A[M][K] * Bt[N][K]^T   (bf16 in, fp32 acc, OutT out) ----
// m97 structure + 16B-chunk XOR swizzle (r5: conflicts 6.29e6 -> 0)
template <typename OutT>
__global__ __launch_bounds__(256) void k_gemm(const u16* __restrict__ A,
                                              const u16* __restrict__ Bt,
                                              OutT* __restrict__ C,
                                              int M, int N, int K) {
  __shared__ __align__(16) u16 As[128 * 32];
  __shared__ __align__(16) u16 Bs[128 * 32];
  const int tid = threadIdx.x;
  const int wv = tid >> 6, lane = tid & 63;
  const int quad = lane >> 4, ln = lane & 15;
  const int wm = wv & 1, wn = wv >> 1;
  const int rchnk = quad ^ ((ln >> 1) & 3);
  const long m0 = (long)blockIdx.x * 128;
  const long n0 = (long)blockIdx.y * 128;
  f32x4 acc[4][4] = {};
  for (int k0 = 0; k0 < K; k0 += 32) {
#pragma unroll
    for (int r = 0; r < 2; ++r) {
      int c = r * 256 + tid;
      int gc = (c & 3) ^ ((c >> 3) & 3);
      gl_lds16(A  + (m0 + (c >> 2)) * K + k0 + gc * 8, &As[(r * 256 + wv * 64) * 8]);
      gl_lds16(Bt + (n0 + (c >> 2)) * K + k0 + gc * 8, &Bs[(r * 256 + wv * 64) * 8]);
    }
    __syncthreads();
    bf16x8 af[4], bg[4];
#pragma unroll
    for (int i = 0; i < 4; ++i)
      af[i] = *(const bf16x8*)&As[(wm * 64 + i * 16 + ln) * 32 + rchnk * 8];
#pragma unroll
    for (int j = 0; j < 4; ++j)
      bg[j] = *(const bf16x8*)&Bs[(wn * 64 + j * 16 + ln) * 32 + rchnk * 8];
#pragma unroll
    for (int i = 0; i < 4; ++i)
#pragma unroll
      for (int j = 0; j < 4; ++j)
        acc[i][j] = __builtin_amdgcn_mfma_f32_16x16x32_bf16(af[i], bg[j], acc[i][j], 0, 0, 0);
    __syncthreads();
  }
#pragma unroll
  for (int i = 0; i < 4; ++i) {
    long row = m0 + wm * 64 + i * 16 + quad * 4;
#pragma unroll
    for (int j = 0; j < 4; ++j) {
      long col = n0 + wn * 64 + j * 16 + ln;
#pragma unroll
      for (int r = 0; r < 4; ++r)
        storev(&C[(row + r) * N + col], acc[i][j][r]);
    }
  }
}

// ---- fixed-rebase P emit for one 16x64 score strip ----
// S in MFMA C-layout: S[nt][r] = S[row=quad*4+r][col=nt*16+ln].
// P = exp2(S - 8): no running max / alpha / rescale. Exact up to bf16
// rounding of P (ratios cancel in O = sum(P V)/sum(P); overflow would need
// scores ~130 sigma). Writes P (bf16) with 16B-chunk XOR swizzle.
template <bool DIAG>
__device__ __forceinline__ void p_emit(f32x4 (&S)[4], u16* __restrict__ Pb,
                                       int quad, int ln, int mrow) {
#pragma unroll
  for (int nt = 0; nt < 4; ++nt)
#pragma unroll
    for (int r = 0; r < 4; ++r) {
      float v = S[nt][r];
      if (DIAG) v = (nt * 16 + ln <= mrow + r) ? v : -1e30f;
      float pv = exp2f(v - 8.0f);
      int row = quad * 4 + r;
      int chnk = (nt * 2 + (ln >> 3)) ^ (row & 7);
      *(__bf16*)&Pb[row * 64 + chnk * 8 + (ln & 7)] = (__bf16)pv;
    }
}

// ---- causal GQA flash attention: pair-balanced, fixed-rebase softmax ----
// Block p handles q-tiles {31-p, p}: uniform 33 strip-tiles of work. Each
// wave owns a 16-row strip of BOTH tiles (ILP: two independent chains in one
// wave); K/V LDS tiles and register fragments shared between strips. l via
// P x ones MFMA. Iterations are independent accumulations -> GEMM-like
// pipelining. All LDS uses 16B-chunk XOR swizzle (0 bank conflicts, r2).
__global__ __launch_bounds__(256, 2) void k_attn(const u16* __restrict__ Q,
                                                 const u16* __restrict__ Kg,
                                                 const u16* __restrict__ Vt,
                                                 u16* __restrict__ Og) {
  __shared__ __align__(16) u16 Ks[64 * 128];     // [key][hd], swizzled chunks
  __shared__ __align__(16) u16 Vs[128 * 64];     // [hd][key], swizzled chunks
  __shared__ __align__(16) u16 Ps[4][2][16 * 64]; // per-wave, per-strip P
  const int tid = threadIdx.x;
  const int wv = tid >> 6, lane = tid & 63;
  const int quad = lane >> 4, ln = lane & 15;
  const int bh = blockIdx.y;
  const int b = bh >> 4, h = bh & 15;
  const int kvh = h >> 2;
  const int p = blockIdx.x;
  const int thi = 31 - p, tlo = p;
  const int qhi = thi * 64 + wv * 16;   // global q-row base, hi strip
  const int qlo = tlo * 64 + wv * 16;

  bf16x8 qfh[4], qfl[4];
  {
    const u16* qp = Q + ((long)bh * T_SEQ + qhi + ln) * HD + quad * 8;
#pragma unroll
    for (int s = 0; s < 4; ++s) qfh[s] = *(const bf16x8*)(qp + s * 32);
    qp = Q + ((long)bh * T_SEQ + qlo + ln) * HD + quad * 8;
#pragma unroll
    for (int s = 0; s < 4; ++s) qfl[s] = *(const bf16x8*)(qp + s * 32);
  }
  bf16x8 onesb;
#pragma unroll
  for (int i = 0; i < 8; ++i) onesb[i] = (__bf16)1.0f;

  f32x4 lh = {0.f, 0.f, 0.f, 0.f}, ll = {0.f, 0.f, 0.f, 0.f};
  f32x4 oh[8] = {}, ol[8] = {};

  const u16* Kb = Kg + (long)(b * NKV + kvh) * T_SEQ * HD;
  const u16* Vb = Vt + (long)(b * NKV + kvh) * HD * T_SEQ;

  for (int kt = 0; kt <= thi; ++kt) {
    const int k0 = kt * 64;
#pragma unroll
    for (int r = 0; r < 4; ++r) {
      int s = r * 256 + tid;
      gl_lds16(Kb + (long)(k0 + (s >> 4)) * HD + (((s & 15) ^ ((s >> 4) & 15)) << 3),
               &Ks[(r * 256 + wv * 64) * 8]);
      gl_lds16(Vb + (long)(s >> 3) * T_SEQ + k0 + (((s & 7) ^ ((s >> 3) & 7)) << 3),
               &Vs[(r * 256 + wv * 64) * 8]);
    }
    __syncthreads();
    const bool lo_act = (kt <= tlo);
    f32x4 Sh[4], Sl[4];
#pragma unroll
    for (int nt = 0; nt < 4; ++nt) {
      bf16x8 kb[4];
      const u16* kp = &Ks[(nt * 16 + ln) * 128];
#pragma unroll
      for (int ss = 0; ss < 4; ++ss)
        kb[ss] = *(const bf16x8*)(kp + (((quad + 4 * ss) ^ ln) << 3));
      f32x4 s = {0.f, 0.f, 0.f, 0.f};
#pragma unroll
      for (int ss = 0; ss < 4; ++ss)
        s = __builtin_amdgcn_mfma_f32_16x16x32_bf16(qfh[ss], kb[ss], s, 0, 0, 0);
      Sh[nt] = s;
      if (lo_act) {
        f32x4 t = {0.f, 0.f, 0.f, 0.f};
#pragma unroll
        for (int ss = 0; ss < 4; ++ss)
          t = __builtin_amdgcn_mfma_f32_16x16x32_bf16(qfl[ss], kb[ss], t, 0, 0, 0);
        Sl[nt] = t;
      }
    }
    if (kt == thi) p_emit<true>(Sh, &Ps[wv][0][0], quad, ln, wv * 16 + quad * 4);
    else           p_emit<false>(Sh, &Ps[wv][0][0], quad, ln, 0);
    if (lo_act) {
      if (kt == tlo) p_emit<true>(Sl, &Ps[wv][1][0], quad, ln, wv * 16 + quad * 4);
      else           p_emit<false>(Sl, &Ps[wv][1][0], quad, ln, 0);
    }
    // drain P ds_writes before same-wave cross-lane readback
    asm volatile("s_waitcnt lgkmcnt(0)" ::: "memory");
    bf16x8 pfh[2], pfl[2];
#pragma unroll
    for (int ss = 0; ss < 2; ++ss)
      pfh[ss] = *(const bf16x8*)&Ps[wv][0][ln * 64 + (((ss * 4 + quad) ^ (ln & 7)) << 3)];
    if (lo_act) {
#pragma unroll
      for (int ss = 0; ss < 2; ++ss)
        pfl[ss] = *(const bf16x8*)&Ps[wv][1][ln * 64 + (((ss * 4 + quad) ^ (ln & 7)) << 3)];
    }
    // l += P . ones (row-sums via MFMA; no shuffle reduction)
    lh = __builtin_amdgcn_mfma_f32_16x16x32_bf16(pfh[0], onesb, lh, 0, 0, 0);
    lh = __builtin_amdgcn_mfma_f32_16x16x32_bf16(pfh[1], onesb, lh, 0, 0, 0);
    if (lo_act) {
      ll = __builtin_amdgcn_mfma_f32_16x16x32_bf16(pfl[0], onesb, ll, 0, 0, 0);
      ll = __builtin_amdgcn_mfma_f32_16x16x32_bf16(pfl[1], onesb, ll, 0, 0, 0);
    }
    // O += P V, sharing V fragments between strips
#pragma unroll
    for (int dt = 0; dt < 8; ++dt) {
      bf16x8 vb[2];
      const u16* vp = &Vs[(dt * 16 + ln) * 64];
#pragma unroll
      for (int ss = 0; ss < 2; ++ss)
        vb[ss] = *(const bf16x8*)(vp + (((quad + 4 * ss) ^ (ln & 7)) << 3));
#pragma unroll
      for (int ss = 0; ss < 2; ++ss)
        oh[dt] = __builtin_amdgcn_mfma_f32_16x16x32_bf16(pfh[ss], vb[ss], oh[dt], 0, 0, 0);
      if (lo_act) {
#pragma unroll
        for (int ss = 0; ss < 2; ++ss)
          ol[dt] = __builtin_amdgcn_mfma_f32_16x16x32_bf16(pfl[ss], vb[ss], ol[dt], 0, 0, 0);
      }
    }
    __syncthreads();
  }
  float rh[4], rl[4];
#pragma unroll
  for (int r = 0; r < 4; ++r) { rh[r] = 1.f / lh[r]; rl[r] = 1.f / ll[r]; }
#pragma unroll
  for (int dt = 0; dt < 8; ++dt)
#pragma unroll
    for (int r = 0; r < 4; ++r) {
      long rowh = (long)b * T_SEQ + qhi + quad * 4 + r;
      long rowl = (long)b * T_SEQ + qlo + quad * 4 + r;
      Og[rowh * (NH * HD) + h * HD + dt * 16 + ln] = f2b(oh[dt][r] * rh[r]);
      Og[rowl * (NH * HD) + h * HD + dt * 16 + ln] = f2b(ol[dt][r] * rl[r]);
    }
}

extern "C" void kernel_launch(void* const* d_in, const int* in_sizes, int n_in,
                              void* d_out, int out_size, void* d_ws, size_t ws_size,
                              hipStream_t stream) {
  const float* x  = (const float*)d_in[0];
  const float* Wq = (const float*)d_in[1];
  const float* Wk = (const float*)d_in[2];
  const float* Wv = (const float*)d_in[3];
  const float* Wo = (const float*)d_in[4];
  float* out = (float*)d_out;
  char* ws = (char*)d_ws;
  // workspace layout (bytes), total ~63 MB
  u16* WT  = (u16*)(ws + 0);          // [3072][2048] bf16  (Wq^T | Wk^T | Wv^T)
  u16* Wot = (u16*)(ws + 12582912);   // [2048][2048] bf16
  u16* Xb  = (u16*)(ws + 20971520);   // [4096][2048] bf16 ; aliased by attn
  u16* Qb  = (u16*)(ws + 37748736);   // [B,NH,T,HD] bf16
  u16* Kb  = (u16*)(ws + 54525952);   // [B,NKV,T,HD] bf16
  u16* Vtb = (u16*)(ws + 58720256);   // [B,NKV,HD,T] bf16
  u16* attn = Xb;   // alias: Xb dead after QKV GEMM

  k_cvt_x<<<8192, 256, 0, stream>>>(x, Xb, MROWS * DM);
  k_tw4<<<dim3(1, 64, 160), dim3(32, 8), 0, stream>>>(Wq, Wk, Wv, Wo, WT, Wot);

  k_gemm_qkv<<<dim3(32, 24), 256, 0, stream>>>(Xb, WT, Qb, Kb, Vtb);

  k_attn<<<dim3(16, 32), 256, 0, stream>>>(Qb, Kb, Vtb, attn);

  k_gemm<float><<<dim3(32, 16), 256, 0, stream>>>(attn, Wot, out, MROWS, DM, 2048);
}

// Round 7
// 317.322 us; speedup vs baseline: 1.1068x; 1.1068x over previous
//
#include <hip/hip_runtime.h>
#include <stdint.h>

#define T_SEQ 2048
#define DM    2048
#define NH    16
#define NKV   4
#define HD    128
#define MROWS 4096          // B*T
#define NQKV  3072          // 16*128 + 4*128 + 4*128

typedef unsigned short u16;
typedef __bf16 bf16x8 __attribute__((ext_vector_type(8)));
typedef float  f32x4  __attribute__((ext_vector_type(4)));
typedef u16    u16x8  __attribute__((ext_vector_type(8)));

__device__ __forceinline__ u16 f2b(float f) {
  union { float f; unsigned u; } v; v.f = f;
  return (u16)((v.u + 0x7fffu + ((v.u >> 16) & 1u)) >> 16);
}
__device__ __forceinline__ float b2f(u16 u) {
  union { unsigned u; float f; } v; v.u = ((unsigned)u) << 16;
  return v.f;
}
// async global->LDS, 16B per lane; LDS dest = wave-uniform base + lane*16
__device__ __forceinline__ void gl_lds16(const u16* g, u16* l) {
  __builtin_amdgcn_global_load_lds(
      (__attribute__((address_space(1))) void*)g,
      (__attribute__((address_space(3))) void*)l, 16, 0, 0);
}
__device__ __forceinline__ void storev(float* p, float v) { *p = v; }
__device__ __forceinline__ void storev(u16* p, float v)   { *p = f2b(v); }

// ---- merged prep: 4 weight transposes + x fp32->bf16 cast, one launch ----
// z<160: transpose tiles ([0,64) Wq->WT, [64,80) Wk, [80,96) Wv, [96,160) Wo)
// z in [160,288): cvt path, linear block id (z-160)*64 + y, 1024 elems/block.
__global__ __launch_bounds__(256) void k_prep(const float* __restrict__ x,
                                              const float* __restrict__ Wq,
                                              const float* __restrict__ Wk,
                                              const float* __restrict__ Wv,
                                              const float* __restrict__ Wo,
                                              u16* __restrict__ Xb,
                                              u16* __restrict__ WT,
                                              u16* __restrict__ Wot) {
  int z = blockIdx.z;
  int tx = threadIdx.x, ty = threadIdx.y;
  if (z >= 160) {
    int lid = (z - 160) * 64 + blockIdx.y;
    int i = (lid * 256 + ty * 32 + tx) * 4;
    float4 v = *(const float4*)(x + i);
    ushort4 r;
    r.x = f2b(v.x); r.y = f2b(v.y); r.z = f2b(v.z); r.w = f2b(v.w);
    *(ushort4*)(Xb + i) = r;
    return;
  }
  __shared__ float tl[32][33];
  const float* in; u16* out; int Nd, xt;
  if (z < 64)      { in = Wq; out = WT;               Nd = 2048; xt = z; }
  else if (z < 80) { in = Wk; out = WT + 2048 * 2048; Nd = 512;  xt = z - 64; }
  else if (z < 96) { in = Wv; out = WT + 2560 * 2048; Nd = 512;  xt = z - 80; }
  else             { in = Wo; out = Wot;              Nd = 2048; xt = z - 96; }
  int n0 = xt * 32, k0 = blockIdx.y * 32;
#pragma unroll
  for (int i = 0; i < 32; i += 8)
    tl[ty + i][tx] = in[(long)(k0 + ty + i) * Nd + n0 + tx];
  __syncthreads();
#pragma unroll
  for (int i = 0; i < 32; i += 8)
    out[(long)(n0 + ty + i) * 2048 + k0 + tx] = f2b(tl[tx][ty + i]);
}

// ---- fused QKV GEMM: C = Xb * WT^T with RoPE/V-transpose epilogue ----
// m97 K-loop + chunk-XOR swizzle (r5: 0 conflicts). Each C-tile is 128 t x
// 128 d = one head (by<16: Q head; 16-19: K; 20-23: V).
// r6 LESSON: computing RoPE while acc was still live cost VGPR 132 ->
// occupancy 10.8% -> 120 us. Fix: dump the WHOLE tile to LDS first (acc dies
// before any sincos), one barrier, then a low-register RoPE pass (2
// threads/row, u16x8 chunks, coalesced 16B stores to final [B,H,T,HD]).
// Q pre-scaled by (1/sqrt(128))*log2(e) for the exp2-domain attention.
// V: direct transposed ushort4 stores from acc (cheap registers).
__global__ __launch_bounds__(256) void k_gemm_qkv(const u16* __restrict__ A,
                                                  const u16* __restrict__ Bt,
                                                  u16* __restrict__ Qo,
                                                  u16* __restrict__ Ko,
                                                  u16* __restrict__ Vo) {
  __shared__ __align__(16) u16 smem[128 * 136];  // 34816 B; As/Bs alias front
  u16* As = smem;
  u16* Bs = smem + 4096;
  const int tid = threadIdx.x;
  const int wv = tid >> 6, lane = tid & 63;
  const int quad = lane >> 4, ln = lane & 15;
  const int wm = wv & 1, wn = wv >> 1;
  const int rchnk = quad ^ ((ln >> 1) & 3);
  const int m0i = blockIdx.x * 128;
  const int by = blockIdx.y;
  const long m0 = m0i, n0 = (long)by * 128;
  f32x4 acc[4][4] = {};
  for (int k0 = 0; k0 < DM; k0 += 32) {
#pragma unroll
    for (int r = 0; r < 2; ++r) {
      int c = r * 256 + tid;
      int gc = (c & 3) ^ ((c >> 3) & 3);
      gl_lds16(A  + (m0 + (c >> 2)) * DM + k0 + gc * 8, &As[(r * 256 + wv * 64) * 8]);
      gl_lds16(Bt + (n0 + (c >> 2)) * DM + k0 + gc * 8, &Bs[(r * 256 + wv * 64) * 8]);
    }
    __syncthreads();
    bf16x8 af[4], bg[4];
#pragma unroll
    for (int i = 0; i < 4; ++i)
      af[i] = *(const bf16x8*)&As[(wm * 64 + i * 16 + ln) * 32 + rchnk * 8];
#pragma unroll
    for (int j = 0; j < 4; ++j)
      bg[j] = *(const bf16x8*)&Bs[(wn * 64 + j * 16 + ln) * 32 + rchnk * 8];
#pragma unroll
    for (int i = 0; i < 4; ++i)
#pragma unroll
      for (int j = 0; j < 4; ++j)
        acc[i][j] = __builtin_amdgcn_mfma_f32_16x16x32_bf16(af[i], bg[j], acc[i][j], 0, 0, 0);
    __syncthreads();
  }
  if (by < 20) {
    // ---- stage full tile to LDS; acc dies here, BEFORE any RoPE math ----
#pragma unroll
    for (int i = 0; i < 4; ++i)
#pragma unroll
      for (int j = 0; j < 4; ++j)
#pragma unroll
        for (int r = 0; r < 4; ++r)
          smem[(wm * 64 + i * 16 + quad * 4 + r) * 136 + wn * 64 + j * 16 + ln] =
              f2b(acc[i][j][r]);
    __syncthreads();
    const bool isQ = by < 16;
    const int head = isQ ? by : by - 16;
    const int nh = isQ ? NH : NKV;
    const float qs = isQ ? 0.12751745f : 1.0f;   // (1/sqrt(128))*log2(e) | 1
    u16* dst = isQ ? Qo : Ko;
    const int row = tid >> 1, a = tid & 1;       // 2 threads per t-row
    const int t = m0i + row;
    const int t2 = t & (T_SEQ - 1), bb = t >> 11;
    const u16* cr = &smem[row * 136 + a * 32];
    const long ob = ((long)(bb * nh + head) * T_SEQ + t2) * HD + a * 32;
    const float tf = (float)t2;
#pragma unroll
    for (int g = 0; g < 4; ++g) {
      u16x8 oA, oB;
#pragma unroll
      for (int dd = 0; dd < 8; ++dd) {
        int d = a * 32 + g * 8 + dd;
        float c1 = b2f(cr[g * 8 + dd]);
        float c2 = b2f(cr[g * 8 + dd + 64]);
        float inv = __expf(-0.14391156f * (float)d);  // 10000^(-d/64)
        float sn, cn;
        __sincosf(tf * inv, &sn, &cn);
        oA[dd] = f2b((c1 * cn - c2 * sn) * qs);
        oB[dd] = f2b((c2 * cn + c1 * sn) * qs);
      }
      *(u16x8*)&dst[ob + g * 8]      = oA;
      *(u16x8*)&dst[ob + 64 + g * 8] = oB;
    }
  } else {
    // ---- V: direct transposed stores into Vt[B,KV,HD,T] ----
    const int kv = by - 20;
    const int bb = m0i >> 11, t0i = m0i & (T_SEQ - 1);
#pragma unroll
    for (int i = 0; i < 4; ++i)
#pragma unroll
      for (int j = 0; j < 4; ++j) {
        int d = wn * 64 + j * 16 + ln;
        int t = t0i + wm * 64 + i * 16 + quad * 4;
        long vo = ((long)((bb * NKV + kv) * HD) + d) * T_SEQ + t;
        ushort4 pk;
        pk.x = f2b(acc[i][j][0]); pk.y = f2b(acc[i][j][1]);
        pk.z = f2b(acc[i][j][2]); pk.w = f2b(acc[i][j][3]);
        *(ushort4*)&Vo[vo] = pk;
      }
  }
}

// ---- C[M][N] = A[M][K] * Bt[N][K]^T   (bf16 in, fp32 acc, OutT out) ----
// m97 structure + 16B-chunk XOR swizzle (r5: conflicts 6.29e6 -> 0)
template <typename OutT>
__global__ __launch_bounds__(256) void k_gemm(const u16* __restrict__ A,
                                              const u16* __restrict__ Bt,
                                              OutT* __restrict__ C,
                                              int M, int N, int K) {
  __shared__ __align__(16) u16 As[128 * 32];
  __shared__ __align__(16) u16 Bs[128 * 32];
  const int tid = threadIdx.x;
  const int wv = tid >> 6, lane = tid & 63;
  const int quad = lane >> 4, ln = lane & 15;
  const int wm = wv & 1, wn = wv >> 1;
  const int rchnk = quad ^ ((ln >> 1) & 3);
  const long m0 = (long)blockIdx.x * 128;
  const long n0 = (long)blockIdx.y * 128;
  f32x4 acc[4][4] = {};
  for (int k0 = 0; k0 < K; k0 += 32) {
#pragma unroll
    for (int r = 0; r < 2; ++r) {
      int c = r * 256 + tid;
      int gc = (c & 3) ^ ((c >> 3) & 3);
      gl_lds16(A  + (m0 + (c >> 2)) * K + k0 + gc * 8, &As[(r * 256 + wv * 64) * 8]);
      gl_lds16(Bt + (n0 + (c >> 2)) * K + k0 + gc * 8, &Bs[(r * 256 + wv * 64) * 8]);
    }
    __syncthreads();
    bf16x8 af[4], bg[4];
#pragma unroll
    for (int i = 0; i < 4; ++i)
      af[i] = *(const bf16x8*)&As[(wm * 64 + i * 16 + ln) * 32 + rchnk * 8];
#pragma unroll
    for (int j = 0; j < 4; ++j)
      bg[j] = *(const bf16x8*)&Bs[(wn * 64 + j * 16 + ln) * 32 + rchnk * 8];
#pragma unroll
    for (int i = 0; i < 4; ++i)
#pragma unroll
      for (int j = 0; j < 4; ++j)
        acc[i][j] = __builtin_amdgcn_mfma_f32_16x16x32_bf16(af[i], bg[j], acc[i][j], 0, 0, 0);
    __syncthreads();
  }
#pragma unroll
  for (int i = 0; i < 4; ++i) {
    long row = m0 + wm * 64 + i * 16 + quad * 4;
#pragma unroll
    for (int j = 0; j < 4; ++j) {
      long col = n0 + wn * 64 + j * 16 + ln;
#pragma unroll
      for (int r = 0; r < 4; ++r)
        storev(&C[(row + r) * N + col], acc[i][j][r]);
    }
  }
}

// ---- fixed-rebase P emit for one 16x64 score strip ----
// S in MFMA C-layout: S[nt][r] = S[row=quad*4+r][col=nt*16+ln].
// P = exp2(S - 8): no running max / alpha / rescale. Exact up to bf16
// rounding of P (ratios cancel in O = sum(P V)/sum(P); overflow would need
// scores ~130 sigma). Writes P (bf16) with 16B-chunk XOR swizzle.
template <bool DIAG>
__device__ __forceinline__ void p_emit(f32x4 (&S)[4], u16* __restrict__ Pb,
                                       int quad, int ln, int mrow) {
#pragma unroll
  for (int nt = 0; nt < 4; ++nt)
#pragma unroll
    for (int r = 0; r < 4; ++r) {
      float v = S[nt][r];
      if (DIAG) v = (nt * 16 + ln <= mrow + r) ? v : -1e30f;
      float pv = exp2f(v - 8.0f);
      int row = quad * 4 + r;
      int chnk = (nt * 2 + (ln >> 3)) ^ (row & 7);
      *(__bf16*)&Pb[row * 64 + chnk * 8 + (ln & 7)] = (__bf16)pv;
    }
}

// ---- causal GQA flash attention: pair-balanced, fixed-rebase softmax ----
// Block p handles q-tiles {31-p, p}: uniform 33 strip-tiles of work. Each
// wave owns a 16-row strip of BOTH tiles (ILP: two independent chains in one
// wave); K/V LDS tiles and register fragments shared between strips. l via
// P x ones MFMA. Iterations are independent accumulations -> GEMM-like
// pipelining. All LDS uses 16B-chunk XOR swizzle (0 bank conflicts, r2).
__global__ __launch_bounds__(256, 2) void k_attn(const u16* __restrict__ Q,
                                                 const u16* __restrict__ Kg,
                                                 const u16* __restrict__ Vt,
                                                 u16* __restrict__ Og) {
  __shared__ __align__(16) u16 Ks[64 * 128];     // [key][hd], swizzled chunks
  __shared__ __align__(16) u16 Vs[128 * 64];     // [hd][key], swizzled chunks
  __shared__ __align__(16) u16 Ps[4][2][16 * 64]; // per-wave, per-strip P
  const int tid = threadIdx.x;
  const int wv = tid >> 6, lane = tid & 63;
  const int quad = lane >> 4, ln = lane & 15;
  const int bh = blockIdx.y;
  const int b = bh >> 4, h = bh & 15;
  const int kvh = h >> 2;
  const int p = blockIdx.x;
  const int thi = 31 - p, tlo = p;
  const int qhi = thi * 64 + wv * 16;   // global q-row base, hi strip
  const int qlo = tlo * 64 + wv * 16;

  bf16x8 qfh[4], qfl[4];
  {
    const u16* qp = Q + ((long)bh * T_SEQ + qhi + ln) * HD + quad * 8;
#pragma unroll
    for (int s = 0; s < 4; ++s) qfh[s] = *(const bf16x8*)(qp + s * 32);
    qp = Q + ((long)bh * T_SEQ + qlo + ln) * HD + quad * 8;
#pragma unroll
    for (int s = 0; s < 4; ++s) qfl[s] = *(const bf16x8*)(qp + s * 32);
  }
  bf16x8 onesb;
#pragma unroll
  for (int i = 0; i < 8; ++i) onesb[i] = (__bf16)1.0f;

  f32x4 lh = {0.f, 0.f, 0.f, 0.f}, ll = {0.f, 0.f, 0.f, 0.f};
  f32x4 oh[8] = {}, ol[8] = {};

  const u16* Kb = Kg + (long)(b * NKV + kvh) * T_SEQ * HD;
  const u16* Vb = Vt + (long)(b * NKV + kvh) * HD * T_SEQ;

  for (int kt = 0; kt <= thi; ++kt) {
    const int k0 = kt * 64;
#pragma unroll
    for (int r = 0; r < 4; ++r) {
      int s = r * 256 + tid;
      gl_lds16(Kb + (long)(k0 + (s >> 4)) * HD + (((s & 15) ^ ((s >> 4) & 15)) << 3),
               &Ks[(r * 256 + wv * 64) * 8]);
      gl_lds16(Vb + (long)(s >> 3) * T_SEQ + k0 + (((s & 7) ^ ((s >> 3) & 7)) << 3),
               &Vs[(r * 256 + wv * 64) * 8]);
    }
    __syncthreads();
    const bool lo_act = (kt <= tlo);
    f32x4 Sh[4], Sl[4];
#pragma unroll
    for (int nt = 0; nt < 4; ++nt) {
      bf16x8 kb[4];
      const u16* kp = &Ks[(nt * 16 + ln) * 128];
#pragma unroll
      for (int ss = 0; ss < 4; ++ss)
        kb[ss] = *(const bf16x8*)(kp + (((quad + 4 * ss) ^ ln) << 3));
      f32x4 s = {0.f, 0.f, 0.f, 0.f};
#pragma unroll
      for (int ss = 0; ss < 4; ++ss)
        s = __builtin_amdgcn_mfma_f32_16x16x32_bf16(qfh[ss], kb[ss], s, 0, 0, 0);
      Sh[nt] = s;
      if (lo_act) {
        f32x4 t = {0.f, 0.f, 0.f, 0.f};
#pragma unroll
        for (int ss = 0; ss < 4; ++ss)
          t = __builtin_amdgcn_mfma_f32_16x16x32_bf16(qfl[ss], kb[ss], t, 0, 0, 0);
        Sl[nt] = t;
      }
    }
    if (kt == thi) p_emit<true>(Sh, &Ps[wv][0][0], quad, ln, wv * 16 + quad * 4);
    else           p_emit<false>(Sh, &Ps[wv][0][0], quad, ln, 0);
    if (lo_act) {
      if (kt == tlo) p_emit<true>(Sl, &Ps[wv][1][0], quad, ln, wv * 16 + quad * 4);
      else           p_emit<false>(Sl, &Ps[wv][1][0], quad, ln, 0);
    }
    // drain P ds_writes before same-wave cross-lane readback
    asm volatile("s_waitcnt lgkmcnt(0)" ::: "memory");
    bf16x8 pfh[2], pfl[2];
#pragma unroll
    for (int ss = 0; ss < 2; ++ss)
      pfh[ss] = *(const bf16x8*)&Ps[wv][0][ln * 64 + (((ss * 4 + quad) ^ (ln & 7)) << 3)];
    if (lo_act) {
#pragma unroll
      for (int ss = 0; ss < 2; ++ss)
        pfl[ss] = *(const bf16x8*)&Ps[wv][1][ln * 64 + (((ss * 4 + quad) ^ (ln & 7)) << 3)];
    }
    // l += P . ones (row-sums via MFMA; no shuffle reduction)
    lh = __builtin_amdgcn_mfma_f32_16x16x32_bf16(pfh[0], onesb, lh, 0, 0, 0);
    lh = __builtin_amdgcn_mfma_f32_16x16x32_bf16(pfh[1], onesb, lh, 0, 0, 0);
    if (lo_act) {
      ll = __builtin_amdgcn_mfma_f32_16x16x32_bf16(pfl[0], onesb, ll, 0, 0, 0);
      ll = __builtin_amdgcn_mfma_f32_16x16x32_bf16(pfl[1], onesb, ll, 0, 0, 0);
    }
    // O += P V, sharing V fragments between strips
#pragma unroll
    for (int dt = 0; dt < 8; ++dt) {
      bf16x8 vb[2];
      const u16* vp = &Vs[(dt * 16 + ln) * 64];
#pragma unroll
      for (int ss = 0; ss < 2; ++ss)
        vb[ss] = *(const bf16x8*)(vp + (((quad + 4 * ss) ^ (ln & 7)) << 3));
#pragma unroll
      for (int ss = 0; ss < 2; ++ss)
        oh[dt] = __builtin_amdgcn_mfma_f32_16x16x32_bf16(pfh[ss], vb[ss], oh[dt], 0, 0, 0);
      if (lo_act) {
#pragma unroll
        for (int ss = 0; ss < 2; ++ss)
          ol[dt] = __builtin_amdgcn_mfma_f32_16x16x32_bf16(pfl[ss], vb[ss], ol[dt], 0, 0, 0);
      }
    }
    __syncthreads();
  }
  float rh[4], rl[4];
#pragma unroll
  for (int r = 0; r < 4; ++r) { rh[r] = 1.f / lh[r]; rl[r] = 1.f / ll[r]; }
#pragma unroll
  for (int dt = 0; dt < 8; ++dt)
#pragma unroll
    for (int r = 0; r < 4; ++r) {
      long rowh = (long)b * T_SEQ + qhi + quad * 4 + r;
      long rowl = (long)b * T_SEQ + qlo + quad * 4 + r;
      Og[rowh * (NH * HD) + h * HD + dt * 16 + ln] = f2b(oh[dt][r] * rh[r]);
      Og[rowl * (NH * HD) + h * HD + dt * 16 + ln] = f2b(ol[dt][r] * rl[r]);
    }
}

extern "C" void kernel_launch(void* const* d_in, const int* in_sizes, int n_in,
                              void* d_out, int out_size, void* d_ws, size_t ws_size,
                              hipStream_t stream) {
  const float* x  = (const float*)d_in[0];
  const float* Wq = (const float*)d_in[1];
  const float* Wk = (const float*)d_in[2];
  const float* Wv = (const float*)d_in[3];
  const float* Wo = (const float*)d_in[4];
  float* out = (float*)d_out;
  char* ws = (char*)d_ws;
  // workspace layout (bytes), total ~63 MB
  u16* WT  = (u16*)(ws + 0);          // [3072][2048] bf16  (Wq^T | Wk^T | Wv^T)
  u16* Wot = (u16*)(ws + 12582912);   // [2048][2048] bf16
  u16* Xb  = (u16*)(ws + 20971520);   // [4096][2048] bf16 ; aliased by attn
  u16* Qb  = (u16*)(ws + 37748736);   // [B,NH,T,HD] bf16
  u16* Kb  = (u16*)(ws + 54525952);   // [B,NKV,T,HD] bf16
  u16* Vtb = (u16*)(ws + 58720256);   // [B,NKV,HD,T] bf16
  u16* attn = Xb;   // alias: Xb dead after QKV GEMM

  k_prep<<<dim3(1, 64, 288), dim3(32, 8), 0, stream>>>(x, Wq, Wk, Wv, Wo, Xb, WT, Wot);

  k_gemm_qkv<<<dim3(32, 24), 256, 0, stream>>>(Xb, WT, Qb, Kb, Vtb);

  k_attn<<<dim3(16, 32), 256, 0, stream>>>(Qb, Kb, Vtb, attn);

  k_gemm<float><<<dim3(32, 16), 256, 0, stream>>>(attn, Wot, out, MROWS, DM, 2048);
}